// Round 3
// baseline (1199.603 us; speedup 1.0000x reference)
//
#include <hip/hip_runtime.h>
#include <math.h>

#define BATCH  256
#define NQ     1000
#define NC     81
#define QC     81000
#define CHUNKS (QC / 4)   // 20250 float4 chunks per batch
#define TOPK   100
#define NBINS  4096
#define CAP    4096
#define NT     1024

// Precise logistic, matching jax.nn.sigmoid (used for per-q factors and the
// few-hundred final candidates -> ranking bit-identical to the absmax=0 kernel).
__device__ __forceinline__ float sigmoidf(float x) {
    if (x >= 0.f) return 1.f / (1.f + expf(-x));
    float e = expf(x);
    return e / (1.f + e);
}

// Fast branch-free logistic (~1e-5 rel err, <= 1, correct limits).
__device__ __forceinline__ float fast_sig(float x) {
    return __builtin_amdgcn_rcpf(1.f + __expf(-x));
}

struct Smem {
    float    P[NQ];       // exp(-obj)*(1-sig(unk))  — upper bound factor
    float    Pm2[NQ];     // max(P[q], P[q+1])       — chunk skip bound
    float    op[NQ];      // exp(-obj)               (precise)
    float    omun[NQ];    // 1 - sig(unk)            (precise)
    float    last[NQ];    // exp(-obj)*sig(unk)      class 80 (precise)
    unsigned hist[NBINS];
    unsigned coarse[64];
    float    cv[CAP];
    int      ci[CAP];
    unsigned cnt;
    unsigned thr;
};

// Suffix-scan the histogram for the bin where the count from the top reaches
// TOPK. All threads call; internal barriers.
__device__ unsigned scan_threshold(Smem& s, int tid) {
    __syncthreads();
    if (tid < 64) {
        unsigned acc = 0;
        #pragma unroll 8
        for (int j = 0; j < 64; ++j) acc += s.hist[tid * 64 + j];
        s.coarse[tid] = acc;
    }
    __syncthreads();
    if (tid == 0) {
        unsigned acc = 0; int cb = -1;
        for (int i = 63; i >= 0; --i) {
            unsigned v = s.coarse[i];
            if (acc + v >= TOPK) { cb = i; break; }
            acc += v;
        }
        unsigned tb = 0;
        if (cb >= 0) {
            tb = (unsigned)(cb * 64);
            for (int f = cb * 64 + 63; f >= cb * 64; --f) {
                unsigned v = s.hist[f];
                if (acc + v >= TOPK) { tb = (unsigned)f; break; }
                acc += v;
            }
        }
        s.thr = tb;
    }
    __syncthreads();
    return s.thr;
}

__device__ __forceinline__ void do_chunk(Smem& s, const float4& v4, int q, int c,
                                         unsigned thbits, bool do_hist) {
    float xs[4] = {v4.x, v4.y, v4.z, v4.w};
    #pragma unroll
    for (int k = 0; k < 4; ++k) {
        int ck = c + k, qk = q;
        if (ck >= NC) { ck -= NC; ++qk; }
        if (ck < 60) {                       // classes 60..80 handled elsewhere
            float v = s.P[qk] * fast_sig(xs[k]);
            unsigned u = __float_as_uint(v);
            if (u >= thbits) {
                if (do_hist) atomicAdd(&s.hist[u >> 19], 1u);
                float pv = (s.op[qk] * sigmoidf(xs[k])) * s.omun[qk]; // exact ref order
                unsigned p = atomicAdd(&s.cnt, 1u);
                if (p < CAP) { s.cv[p] = pv; s.ci[p] = qk * NC + ck; }
            }
        }
    }
}

// One sweep over all chunks with chunk-level load skipping; 2-way unroll for MLP.
__device__ void scan_chunks(Smem& s, const float4* lg4, unsigned thbits,
                            bool do_hist, int tid) {
    int e = 4 * tid;
    int q = e / NC;
    int c = e - q * NC;
    for (int i4 = tid; i4 < CHUNKS; i4 += 2 * NT) {
        // chunk B index math: +NT chunks = +4096 elements = +50q +46c
        int qb = q + 50, cb = c + 46;
        if (cb >= NC) { cb -= NC; ++qb; }
        bool hasB = (i4 + NT) < CHUNKS;

        float4 va, vb;
        bool da = false, db = false;
        if (__float_as_uint(s.Pm2[q]) >= thbits) { va = lg4[i4]; da = true; }
        if (hasB && __float_as_uint(s.Pm2[qb]) >= thbits) { vb = lg4[i4 + NT]; db = true; }
        if (da) do_chunk(s, va, q, c, thbits, do_hist);
        if (db) do_chunk(s, vb, qb, cb, thbits, do_hist);

        // advance by 2*NT chunks = 8192 elements = +101q +11c
        c += 11; q += 101;
        if (c >= NC) { c -= NC; ++q; }
    }
}

__device__ void collect80(Smem& s, unsigned thbits, int tid) {
    for (int q = tid; q < NQ; q += NT) {
        float v = s.last[q];                 // approx == precise for class 80
        if (__float_as_uint(v) >= thbits) {
            unsigned p = atomicAdd(&s.cnt, 1u);
            if (p < CAP) { s.cv[p] = v; s.ci[p] = q * NC + 80; }
        }
    }
}

__global__ __launch_bounds__(NT) void postprocess_kernel(
    const float* __restrict__ logits,   // [B, Q, C]
    const float* __restrict__ obj,      // [B, Q]
    const float* __restrict__ boxes,    // [B, Q, 4] cx cy w h
    const float* __restrict__ unk,      // [B, Q]
    const float* __restrict__ tsz,      // [B, 2]  (h, w)
    float* __restrict__ out)            // scores[B*K] | labels[B*K] | boxes[B*K*4]
{
    __shared__ Smem s;
    const int b   = blockIdx.x;
    const int tid = threadIdx.x;
    const float4* lg4 = (const float4*)(logits + (size_t)b * QC);

    for (int i = tid; i < NBINS; i += NT) s.hist[i] = 0;
    if (tid == 0) s.cnt = 0;
    for (int q = tid; q < NQ; q += NT) {
        float op = expf(-obj[b * NQ + q]);
        float un = sigmoidf(unk[b * NQ + q]);
        float om = 1.f - un;
        s.op[q] = op; s.omun[q] = om; s.P[q] = op * om; s.last[q] = op * un;
    }
    __syncthreads();

    // class-80 histogram (free: no logit reads) + chunk bound array
    for (int q = tid; q < NQ; q += NT) {
        float pm = s.P[q];
        if (q + 1 < NQ) pm = fmaxf(pm, s.P[q + 1]);
        s.Pm2[q] = pm;
        atomicAdd(&s.hist[__float_as_uint(s.last[q]) >> 19], 1u);
    }

    // provisional threshold t0 (provable lower bound on final threshold)
    unsigned t0  = scan_threshold(s, tid);
    unsigned th0 = (t0 >= 2 ? t0 - 2 : 0) << 19;   // 2-bin (~12%) safety margin

    // single data pass: skip chunks whose row bound can't reach th0
    scan_chunks(s, lg4, th0, /*do_hist=*/true, tid);
    collect80(s, th0, tid);
    __syncthreads();

    // final threshold (histogram complete for all bins >= t0)
    unsigned tF  = scan_threshold(s, tid);
    unsigned thF = (tF >= 2 ? tF - 2 : 0) << 19;

    unsigned total = s.cnt;
    if (total > CAP) {
        // pathological: candidate buffer overflowed; clean rescan at final threshold
        __syncthreads();
        if (tid == 0) s.cnt = 0;
        __syncthreads();
        scan_chunks(s, lg4, thF, /*do_hist=*/false, tid);
        collect80(s, thF, tid);
    }
    __syncthreads();

    const int n = (int)min(s.cnt, (unsigned)CAP);

    // ---- rank (exact, tie-break: lower flat index first, like lax.top_k) ----
    const float* bx = boxes + (size_t)b * NQ * 4;
    const float img_h = tsz[b * 2 + 0];
    const float img_w = tsz[b * 2 + 1];
    float* o_sc = out + (size_t)b * TOPK;
    float* o_lb = out + (size_t)BATCH * TOPK + (size_t)b * TOPK;
    float* o_bx = out + (size_t)2 * BATCH * TOPK + (size_t)b * TOPK * 4;

    for (int i = tid; i < n; i += NT) {
        float vi = s.cv[i];
        int   ei = s.ci[i];
        int r = 0;
        for (int j = 0; j < n; ++j) {
            float vj = s.cv[j];
            int   ej = s.ci[j];
            r += (vj > vi) || (vj == vi && ej < ei);
        }
        if (r < TOPK) {
            o_sc[r] = vi;
            o_lb[r] = (float)(ei % NC);
            int q = ei / NC;
            float cx = bx[q * 4 + 0];
            float cy = bx[q * 4 + 1];
            float w  = bx[q * 4 + 2];
            float h  = bx[q * 4 + 3];
            o_bx[r * 4 + 0] = (cx - 0.5f * w) * img_w;
            o_bx[r * 4 + 1] = (cy - 0.5f * h) * img_h;
            o_bx[r * 4 + 2] = (cx + 0.5f * w) * img_w;
            o_bx[r * 4 + 3] = (cy + 0.5f * h) * img_h;
        }
    }
}

extern "C" void kernel_launch(void* const* d_in, const int* in_sizes, int n_in,
                              void* d_out, int out_size, void* d_ws, size_t ws_size,
                              hipStream_t stream) {
    const float* pred_logits = (const float*)d_in[0];
    const float* pred_obj    = (const float*)d_in[1];
    const float* pred_boxes  = (const float*)d_in[2];
    const float* pred_unk    = (const float*)d_in[3];
    const float* target_sz   = (const float*)d_in[4];
    float* out = (float*)d_out;
    postprocess_kernel<<<BATCH, NT, 0, stream>>>(
        pred_logits, pred_obj, pred_boxes, pred_unk, target_sz, out);
}

// Round 4
// 155.931 us; speedup vs baseline: 7.6932x; 7.6932x over previous
//
#include <hip/hip_runtime.h>
#include <math.h>

#define BATCH  256
#define NQ     1000
#define NC     81
#define QC     81000
#define CHUNKS (QC / 4)   // 20250 float4 chunks per batch
#define TOPK   100
#define NBINS  4096
#define CAP    4096
#define CAP2   1024
#define NT     1024

// Precise logistic, matching jax.nn.sigmoid (per-q factors + final candidates
// -> ranking bit-identical to the absmax=0 kernel).
__device__ __forceinline__ float sigmoidf(float x) {
    if (x >= 0.f) return 1.f / (1.f + expf(-x));
    float e = expf(x);
    return e / (1.f + e);
}

// Fast branch-free logistic (~1e-5 rel err, <= 1+ulp, correct limits).
__device__ __forceinline__ float fast_sig(float x) {
    return __builtin_amdgcn_rcpf(1.f + __expf(-x));
}

struct Smem {
    float    P[NQ];       // exp(-obj)*(1-sig(unk))  — upper bound factor
    float    Pm2[NQ];     // max(P[q], P[q+1])       — chunk skip bound
    float    op[NQ];      // exp(-obj)               (precise)
    float    omun[NQ];    // 1 - sig(unk)            (precise)
    float    last[NQ];    // exp(-obj)*sig(unk)      class 80 (precise)
    unsigned hist[NBINS];
    float    cv[CAP];
    int      ci[CAP];
    float    cv2[CAP2];
    int      ci2[CAP2];
    unsigned cnt;
    unsigned cnt2;
    unsigned thr;
};

// Find largest bin t such that |{keys in bins >= t}| >= TOPK.
// Wave-0 shuffle suffix-scan; all threads call (internal barriers).
__device__ unsigned scan_threshold(Smem& s, int tid) {
    __syncthreads();
    if (tid < 64) {
        // coarse per-lane sums (64 bins each), vectorized LDS reads
        unsigned c = 0;
        #pragma unroll
        for (int j = 0; j < 64; j += 4) {
            uint4 h = *(const uint4*)&s.hist[tid * 64 + j];
            c += h.x + h.y + h.z + h.w;
        }
        // inclusive suffix sum across lanes: S_i = sum_{j>=i} c_j
        unsigned ssum = c;
        #pragma unroll
        for (int off = 1; off < 64; off <<= 1) {
            unsigned o = __shfl_down(ssum, off, 64);
            if (tid + off < 64) ssum += o;
        }
        unsigned long long bal = __ballot(ssum >= TOPK);
        int cb = 63 - __clzll(bal);          // largest coarse bin with S >= TOPK (-1 if none)
        unsigned tb = 0;
        if (cb >= 0) {
            unsigned S_cb = __shfl(ssum, cb, 64);
            unsigned c_cb = __shfl(c, cb, 64);
            unsigned acc  = S_cb - c_cb;     // count strictly above coarse bin cb (< TOPK)
            unsigned f  = s.hist[cb * 64 + tid];
            unsigned fs = f;
            #pragma unroll
            for (int off = 1; off < 64; off <<= 1) {
                unsigned o = __shfl_down(fs, off, 64);
                if (tid + off < 64) fs += o;
            }
            unsigned long long bal2 = __ballot(acc + fs >= TOPK);
            int fb = 63 - __clzll(bal2);     // guaranteed >= 0
            tb = (unsigned)(cb * 64 + fb);
        }
        if (tid == 0) s.thr = tb;
    }
    __syncthreads();
    return s.thr;
}

__device__ __forceinline__ void do_chunk(Smem& s, const float4& v4, int q, int c,
                                         unsigned thbits, bool do_hist) {
    float xs[4] = {v4.x, v4.y, v4.z, v4.w};
    #pragma unroll
    for (int k = 0; k < 4; ++k) {
        int ck = c + k, qk = q;
        if (ck >= NC) { ck -= NC; ++qk; }
        if (ck < 60) {                       // classes 60..80 handled elsewhere
            float v = s.P[qk] * fast_sig(xs[k]);
            unsigned u = __float_as_uint(v);
            if (u >= thbits) {
                if (do_hist) atomicAdd(&s.hist[u >> 19], 1u);
                float pv = (s.op[qk] * sigmoidf(xs[k])) * s.omun[qk]; // exact ref order
                unsigned p = atomicAdd(&s.cnt, 1u);
                if (p < CAP) { s.cv[p] = pv; s.ci[p] = qk * NC + ck; }
            }
        }
    }
}

// One sweep over all chunks with chunk-level load skipping; 2-way unroll for MLP.
__device__ void scan_chunks(Smem& s, const float4* lg4, unsigned thbits,
                            bool do_hist, int tid) {
    int e = 4 * tid;
    int q = e / NC;
    int c = e - q * NC;
    for (int i4 = tid; i4 < CHUNKS; i4 += 2 * NT) {
        // chunk B index math: +NT chunks = +4096 elements = +50q +46c
        int qb = q + 50, cb = c + 46;
        if (cb >= NC) { cb -= NC; ++qb; }
        bool hasB = (i4 + NT) < CHUNKS;

        float4 va, vb;
        bool da = false, db = false;
        if (__float_as_uint(s.Pm2[q]) >= thbits) { va = lg4[i4]; da = true; }
        if (hasB && __float_as_uint(s.Pm2[qb]) >= thbits) { vb = lg4[i4 + NT]; db = true; }
        if (da) do_chunk(s, va, q, c, thbits, do_hist);
        if (db) do_chunk(s, vb, qb, cb, thbits, do_hist);

        // advance by 2*NT chunks = 8192 elements = +101q +11c
        c += 11; q += 101;
        if (c >= NC) { c -= NC; ++q; }
    }
}

__device__ void collect80(Smem& s, unsigned thbits, int tid) {
    for (int q = tid; q < NQ; q += NT) {
        float v = s.last[q];                 // approx == precise for class 80
        if (__float_as_uint(v) >= thbits) {
            unsigned p = atomicAdd(&s.cnt, 1u);
            if (p < CAP) { s.cv[p] = v; s.ci[p] = q * NC + 80; }
        }
    }
}

__global__ __launch_bounds__(NT) void postprocess_kernel(
    const float* __restrict__ logits,   // [B, Q, C]
    const float* __restrict__ obj,      // [B, Q]
    const float* __restrict__ boxes,    // [B, Q, 4] cx cy w h
    const float* __restrict__ unk,      // [B, Q]
    const float* __restrict__ tsz,      // [B, 2]  (h, w)
    float* __restrict__ out)            // scores[B*K] | labels[B*K] | boxes[B*K*4]
{
    __shared__ Smem s;
    const int b   = blockIdx.x;
    const int tid = threadIdx.x;
    const float4* lg4 = (const float4*)(logits + (size_t)b * QC);

    for (int i = tid; i < NBINS; i += NT) s.hist[i] = 0;
    if (tid == 0) { s.cnt = 0; s.cnt2 = 0; }
    for (int q = tid; q < NQ; q += NT) {
        float op = expf(-obj[b * NQ + q]);
        float un = sigmoidf(unk[b * NQ + q]);
        float om = 1.f - un;
        s.op[q] = op; s.omun[q] = om; s.P[q] = op * om; s.last[q] = op * un;
    }
    __syncthreads();

    // class-80 histogram (free: no logit reads) + chunk bound array
    for (int q = tid; q < NQ; q += NT) {
        float pm = s.P[q];
        if (q + 1 < NQ) pm = fmaxf(pm, s.P[q + 1]);
        s.Pm2[q] = pm;
        atomicAdd(&s.hist[__float_as_uint(s.last[q]) >> 19], 1u);
    }

    // provisional threshold t0 (provable lower bound on final threshold)
    unsigned t0  = scan_threshold(s, tid);
    unsigned th0 = (t0 >= 2 ? t0 - 2 : 0) << 19;   // 2-bin (~12%) safety margin

    // single data pass: skip chunks whose row bound can't reach th0
    scan_chunks(s, lg4, th0, /*do_hist=*/true, tid);
    collect80(s, th0, tid);
    __syncthreads();

    // final threshold (histogram complete for all bins >= t0)
    unsigned tF = scan_threshold(s, tid);

    if (s.cnt > CAP) {
        // pathological: candidate buffer overflowed; clean rescan at final threshold
        unsigned thF = (tF >= 2 ? tF - 2 : 0) << 19;
        __syncthreads();
        if (tid == 0) s.cnt = 0;
        __syncthreads();
        scan_chunks(s, lg4, thF, /*do_hist=*/false, tid);
        collect80(s, thF, tid);
        __syncthreads();
    }

    const int n = (int)min(s.cnt, (unsigned)CAP);

    // ---- compact: keep only candidates that can be in the true top-100 ----
    // Elements of the true top-100 have approx key >= tF-1 bin; filter by the
    // precise score against the bin floor of (tF-1) — a provable superset.
    const float vF = __uint_as_float(((tF >= 1) ? tF - 1 : 0) << 19);
    for (int i = tid; i < n; i += NT) {
        float v = s.cv[i];
        if (v >= vF) {
            unsigned p = atomicAdd(&s.cnt2, 1u);
            if (p < CAP2) { s.cv2[p] = v; s.ci2[p] = s.ci[i]; }
        }
    }
    __syncthreads();

    const float* rv; const int* ri; int m;
    if (s.cnt2 <= CAP2) { rv = s.cv2; ri = s.ci2; m = (int)s.cnt2; }
    else                { rv = s.cv;  ri = s.ci;  m = n; }   // fallback: rank full set

    // ---- rank (exact, tie-break: lower flat index first, like lax.top_k) ----
    const float* bx = boxes + (size_t)b * NQ * 4;
    const float img_h = tsz[b * 2 + 0];
    const float img_w = tsz[b * 2 + 1];
    float* o_sc = out + (size_t)b * TOPK;
    float* o_lb = out + (size_t)BATCH * TOPK + (size_t)b * TOPK;
    float* o_bx = out + (size_t)2 * BATCH * TOPK + (size_t)b * TOPK * 4;

    for (int i = tid; i < m; i += NT) {
        float vi = rv[i];
        int   ei = ri[i];
        int r = 0;
        for (int j = 0; j < m; ++j) {
            float vj = rv[j];
            int   ej = ri[j];
            r += (vj > vi) || (vj == vi && ej < ei);
        }
        if (r < TOPK) {
            o_sc[r] = vi;
            o_lb[r] = (float)(ei % NC);
            int q = ei / NC;
            float cx = bx[q * 4 + 0];
            float cy = bx[q * 4 + 1];
            float w  = bx[q * 4 + 2];
            float h  = bx[q * 4 + 3];
            o_bx[r * 4 + 0] = (cx - 0.5f * w) * img_w;
            o_bx[r * 4 + 1] = (cy - 0.5f * h) * img_h;
            o_bx[r * 4 + 2] = (cx + 0.5f * w) * img_w;
            o_bx[r * 4 + 3] = (cy + 0.5f * h) * img_h;
        }
    }
}

extern "C" void kernel_launch(void* const* d_in, const int* in_sizes, int n_in,
                              void* d_out, int out_size, void* d_ws, size_t ws_size,
                              hipStream_t stream) {
    const float* pred_logits = (const float*)d_in[0];
    const float* pred_obj    = (const float*)d_in[1];
    const float* pred_boxes  = (const float*)d_in[2];
    const float* pred_unk    = (const float*)d_in[3];
    const float* target_sz   = (const float*)d_in[4];
    float* out = (float*)d_out;
    postprocess_kernel<<<BATCH, NT, 0, stream>>>(
        pred_logits, pred_obj, pred_boxes, pred_unk, target_sz, out);
}

// Round 5
// 145.300 us; speedup vs baseline: 8.2561x; 1.0732x over previous
//
#include <hip/hip_runtime.h>
#include <math.h>

#define BATCH  256
#define NQ     1000
#define NC     81
#define QC     81000
#define CHUNKS (QC / 4)   // 20250 float4 chunks per batch
#define TOPK   100
#define NBINS  4096
#define CAP    2048
#define NT     1024

// Precise logistic, matching jax.nn.sigmoid (per-q factors + final candidates
// -> ranking bit-identical to the absmax=0 kernel).
__device__ __forceinline__ float sigmoidf(float x) {
    if (x >= 0.f) return 1.f / (1.f + expf(-x));
    float e = expf(x);
    return e / (1.f + e);
}

// Fast branch-free logistic (~1e-5 rel err, key<=P always since rcp(x>=1)<=1).
__device__ __forceinline__ float fast_sig(float x) {
    return __builtin_amdgcn_rcpf(1.f + __expf(-x));
}

struct Smem {
    float    P[NQ];       // exp(-obj)*(1-sig(unk))  — per-row upper bound
    float    Pm2[NQ];     // max(P[q], P[q+1])       — chunk skip bound
    float    op[NQ];      // exp(-obj)               (precise)
    float    omun[NQ];    // 1 - sig(unk)            (precise)
    float    last[NQ];    // exp(-obj)*sig(unk)      class 80 (precise)
    unsigned hist[NBINS];
    uint2    cand[CAP];   // .x = float bits of precise score, .y = flat index
    unsigned cnt;
    unsigned thr;
};

// Largest bin t with |{keys in bins >= t}| >= TOPK. Wave-0 shuffle suffix scan.
__device__ unsigned scan_threshold(Smem& s, int tid) {
    __syncthreads();
    if (tid < 64) {
        unsigned c = 0;
        #pragma unroll
        for (int j = 0; j < 64; j += 4) {
            uint4 h = *(const uint4*)&s.hist[tid * 64 + j];
            c += h.x + h.y + h.z + h.w;
        }
        unsigned ssum = c;
        #pragma unroll
        for (int off = 1; off < 64; off <<= 1) {
            unsigned o = __shfl_down(ssum, off, 64);
            if (tid + off < 64) ssum += o;
        }
        unsigned long long bal = __ballot(ssum >= TOPK);
        int cb = 63 - __clzll(bal);
        unsigned tb = 0;
        if (cb >= 0) {
            unsigned S_cb = __shfl(ssum, cb, 64);
            unsigned c_cb = __shfl(c, cb, 64);
            unsigned acc  = S_cb - c_cb;          // count strictly above coarse bin
            unsigned fs = s.hist[cb * 64 + tid];
            #pragma unroll
            for (int off = 1; off < 64; off <<= 1) {
                unsigned o = __shfl_down(fs, off, 64);
                if (tid + off < 64) fs += o;
            }
            unsigned long long bal2 = __ballot(acc + fs >= TOPK);
            int fb = 63 - __clzll(bal2);
            tb = (unsigned)(cb * 64 + fb);
        }
        if (tid == 0) s.thr = tb;
    }
    __syncthreads();
    return s.thr;
}

__device__ __forceinline__ void chunk_hist(Smem& s, const float4& v4, int q, int c,
                                           unsigned thbits) {
    float xs[4] = {v4.x, v4.y, v4.z, v4.w};
    #pragma unroll
    for (int k = 0; k < 4; ++k) {
        int ck = c + k, qk = q;
        if (ck >= NC) { ck -= NC; ++qk; }
        if (ck < 60) {                       // 60..79 invalid; 80 in class-80 hist
            unsigned u = __float_as_uint(s.P[qk] * fast_sig(xs[k]));
            if (u >= thbits) atomicAdd(&s.hist[u >> 19], 1u);
        }
    }
}

__device__ __forceinline__ void chunk_collect(Smem& s, const float4& v4, int q, int c,
                                              unsigned thbits) {
    float xs[4] = {v4.x, v4.y, v4.z, v4.w};
    #pragma unroll
    for (int k = 0; k < 4; ++k) {
        int ck = c + k, qk = q;
        if (ck >= NC) { ck -= NC; ++qk; }
        if (ck < 60) {
            unsigned u = __float_as_uint(s.P[qk] * fast_sig(xs[k]));
            if (u >= thbits) {
                float pv = (s.op[qk] * sigmoidf(xs[k])) * s.omun[qk]; // exact ref order
                unsigned p = atomicAdd(&s.cnt, 1u);
                if (p < CAP)
                    s.cand[p] = make_uint2(__float_as_uint(pv), (unsigned)(qk * NC + ck));
            }
        }
    }
}

// One sweep with chunk-level load skipping; 4 loads in flight per thread.
template <bool COLLECT>
__device__ void scan(Smem& s, const float4* __restrict__ lg4, unsigned thbits, int tid) {
    int q = (4 * tid) / NC;
    int c = 4 * tid - q * NC;
    for (int base = tid; base < CHUNKS; base += 4 * NT) {
        float4 vv[4]; bool dd[4]; int qs[4], cs[4];
        int qq = q, cc = c;
        #pragma unroll
        for (int t = 0; t < 4; ++t) {
            int i4 = base + t * NT;
            qs[t] = qq; cs[t] = cc;
            dd[t] = (i4 < CHUNKS) && (__float_as_uint(s.Pm2[qq]) >= thbits);
            if (dd[t]) vv[t] = lg4[i4];
            // +NT chunks = +4096 elements = +50q +46c
            cc += 46; qq += 50; if (cc >= NC) { cc -= NC; ++qq; }
        }
        #pragma unroll
        for (int t = 0; t < 4; ++t) if (dd[t]) {
            if (COLLECT) chunk_collect(s, vv[t], qs[t], cs[t], thbits);
            else         chunk_hist   (s, vv[t], qs[t], cs[t], thbits);
        }
        // +4*NT chunks = +16384 elements = +202q +22c
        c += 22; q += 202; if (c >= NC) { c -= NC; ++q; }
    }
}

__device__ void collect80(Smem& s, unsigned thbits, int tid) {
    for (int q = tid; q < NQ; q += NT) {
        unsigned u = __float_as_uint(s.last[q]);   // key == precise for class 80
        if (u >= thbits) {
            unsigned p = atomicAdd(&s.cnt, 1u);
            if (p < CAP) s.cand[p] = make_uint2(u, (unsigned)(q * NC + 80));
        }
    }
}

__global__ __launch_bounds__(NT) void postprocess_kernel(
    const float* __restrict__ logits,   // [B, Q, C]
    const float* __restrict__ obj,      // [B, Q]
    const float* __restrict__ boxes,    // [B, Q, 4] cx cy w h
    const float* __restrict__ unk,      // [B, Q]
    const float* __restrict__ tsz,      // [B, 2]  (h, w)
    float* __restrict__ out)            // scores[B*K] | labels[B*K] | boxes[B*K*4]
{
    __shared__ Smem s;
    const int b   = blockIdx.x;
    const int tid = threadIdx.x;
    const float4* lg4 = (const float4*)(logits + (size_t)b * QC);

    // ---- init ----
    {
        int i = tid * 4;
        *(uint4*)&s.hist[i] = make_uint4(0u, 0u, 0u, 0u);
    }
    if (tid == 0) s.cnt = 0;
    for (int q = tid; q < NQ; q += NT) {
        float op = expf(-obj[b * NQ + q]);
        float un = sigmoidf(unk[b * NQ + q]);
        float om = 1.f - un;
        s.op[q] = op; s.omun[q] = om; s.P[q] = op * om; s.last[q] = op * un;
    }
    __syncthreads();

    // chunk skip bounds + class-80 histogram (no logit reads needed)
    for (int q = tid; q < NQ; q += NT) {
        float pm = s.P[q];
        if (q + 1 < NQ) pm = fmaxf(pm, s.P[q + 1]);
        s.Pm2[q] = pm;
        atomicAdd(&s.hist[__float_as_uint(s.last[q]) >> 19], 1u);
    }

    // provisional threshold from class-80 alone (lower bound on final tF
    // since histogram counts only grow). Self-consistent in key space: any
    // skipped chunk has key <= P <= Pm2 < bin floor, so bins >= t0 stay exact.
    unsigned t0 = scan_threshold(s, tid);

    // ---- pass 1: histogram only (atomics spread over 4096 bins) ----
    scan<false>(s, lg4, t0 << 19, tid);

    // final threshold: largest bin with >= TOPK keys above it
    unsigned tF = scan_threshold(s, tid);

    // ---- pass 2: collect at tF-1 bin (provable top-100 superset: bin width
    // 1/16 relative >> 2e-5 fast-sig error; chunks are subset of pass 1 -> L2 hot)
    unsigned thC = ((tF >= 1) ? tF - 1 : 0) << 19;
    scan<true>(s, lg4, thC, tid);
    collect80(s, thC, tid);
    __syncthreads();

    if (s.cnt > CAP) {
        // massive-tie pathology only; tighten to bin tF and re-collect.
        __syncthreads();
        if (tid == 0) s.cnt = 0;
        __syncthreads();
        scan<true>(s, lg4, tF << 19, tid);
        collect80(s, tF << 19, tid);
        __syncthreads();
    }

    const int m = (int)min(s.cnt, (unsigned)CAP);

    // ---- rank (exact; scores >= 0 so uint bit order == value order;
    //      tie-break lower flat index first, like lax.top_k) ----
    const float* bx = boxes + (size_t)b * NQ * 4;
    const float img_h = tsz[b * 2 + 0];
    const float img_w = tsz[b * 2 + 1];
    float* o_sc = out + (size_t)b * TOPK;
    float* o_lb = out + (size_t)BATCH * TOPK + (size_t)b * TOPK;
    float* o_bx = out + (size_t)2 * BATCH * TOPK + (size_t)b * TOPK * 4;

    for (int i = tid; i < m; i += NT) {
        uint2 ci = s.cand[i];
        int r = 0;
        for (int j = 0; j < m; ++j) {
            uint2 cj = s.cand[j];
            r += (cj.x > ci.x) || (cj.x == ci.x && cj.y < ci.y);
        }
        if (r < TOPK) {
            int ei = (int)ci.y;
            o_sc[r] = __uint_as_float(ci.x);
            o_lb[r] = (float)(ei % NC);
            int q = ei / NC;
            float cx = bx[q * 4 + 0];
            float cy = bx[q * 4 + 1];
            float w  = bx[q * 4 + 2];
            float h  = bx[q * 4 + 3];
            o_bx[r * 4 + 0] = (cx - 0.5f * w) * img_w;
            o_bx[r * 4 + 1] = (cy - 0.5f * h) * img_h;
            o_bx[r * 4 + 2] = (cx + 0.5f * w) * img_w;
            o_bx[r * 4 + 3] = (cy + 0.5f * h) * img_h;
        }
    }
}

extern "C" void kernel_launch(void* const* d_in, const int* in_sizes, int n_in,
                              void* d_out, int out_size, void* d_ws, size_t ws_size,
                              hipStream_t stream) {
    const float* pred_logits = (const float*)d_in[0];
    const float* pred_obj    = (const float*)d_in[1];
    const float* pred_boxes  = (const float*)d_in[2];
    const float* pred_unk    = (const float*)d_in[3];
    const float* target_sz   = (const float*)d_in[4];
    float* out = (float*)d_out;
    postprocess_kernel<<<BATCH, NT, 0, stream>>>(
        pred_logits, pred_obj, pred_boxes, pred_unk, target_sz, out);
}

// Round 6
// 136.822 us; speedup vs baseline: 8.7676x; 1.0620x over previous
//
#include <hip/hip_runtime.h>
#include <math.h>

#define BATCH  256
#define NQ     1000
#define NC     81
#define QC     81000
#define CHUNKS (QC / 4)   // 20250 float4 chunks per batch
#define TOPK   100
#define NBINS  4096
#define CAP    2048
#define NT     1024

// Precise logistic, matching jax.nn.sigmoid (per-q factors + final candidates
// -> ranking bit-identical to the absmax=0 kernel).
__device__ __forceinline__ float sigmoidf(float x) {
    if (x >= 0.f) return 1.f / (1.f + expf(-x));
    float e = expf(x);
    return e / (1.f + e);
}

// Fast branch-free logistic (~1e-5 rel err, correct limits).
__device__ __forceinline__ float fast_sig(float x) {
    return __builtin_amdgcn_rcpf(1.f + __expf(-x));
}

struct Smem {
    float    P[NQ];       // exp(-obj)*(1-sig(unk))  — per-row upper bound
    float    Pm2[NQ];     // max(P[q], P[q+1])       — row/chunk skip bound
    float    op[NQ];      // exp(-obj)               (precise)
    float    omun[NQ];    // 1 - sig(unk)            (precise)
    float    last[NQ];    // exp(-obj)*sig(unk)      class 80 (precise)
    unsigned hist[NBINS];
    uint2    cand[CAP];   // .x = float bits of precise score, .y = flat index
    int      rowlist[NQ];
    unsigned nrows;
    unsigned cnt;
    unsigned thr;
};

// Largest bin t with |{keys in bins >= t}| >= TOPK. Wave-0 shuffle suffix scan.
__device__ unsigned scan_threshold(Smem& s, int tid) {
    __syncthreads();
    if (tid < 64) {
        unsigned c = 0;
        #pragma unroll
        for (int j = 0; j < 64; j += 4) {
            uint4 h = *(const uint4*)&s.hist[tid * 64 + j];
            c += h.x + h.y + h.z + h.w;
        }
        unsigned ssum = c;
        #pragma unroll
        for (int off = 1; off < 64; off <<= 1) {
            unsigned o = __shfl_down(ssum, off, 64);
            if (tid + off < 64) ssum += o;
        }
        unsigned long long bal = __ballot(ssum >= TOPK);
        int cb = 63 - __clzll(bal);
        unsigned tb = 0;
        if (cb >= 0) {
            unsigned S_cb = __shfl(ssum, cb, 64);
            unsigned c_cb = __shfl(c, cb, 64);
            unsigned acc  = S_cb - c_cb;          // count strictly above coarse bin
            unsigned fs = s.hist[cb * 64 + tid];
            #pragma unroll
            for (int off = 1; off < 64; off <<= 1) {
                unsigned o = __shfl_down(fs, off, 64);
                if (tid + off < 64) fs += o;
            }
            unsigned long long bal2 = __ballot(acc + fs >= TOPK);
            int fb = 63 - __clzll(bal2);
            tb = (unsigned)(cb * 64 + fb);
        }
        if (tid == 0) s.thr = tb;
    }
    __syncthreads();
    return s.thr;
}

template <bool COLLECT>
__device__ __forceinline__ void proc_chunk(Smem& s, const float4& v4, int q, int c,
                                           unsigned thbits) {
    float xs[4] = {v4.x, v4.y, v4.z, v4.w};
    #pragma unroll
    for (int k = 0; k < 4; ++k) {
        int ck = c + k, qk = q;
        if (ck >= NC) { ck -= NC; ++qk; }
        if (ck < 60) {                       // 60..79 invalid; 80 via collect80
            unsigned u = __float_as_uint(s.P[qk] * fast_sig(xs[k]));
            if (u >= thbits) {
                if (!COLLECT) {
                    atomicAdd(&s.hist[u >> 19], 1u);
                } else {
                    float pv = (s.op[qk] * sigmoidf(xs[k])) * s.omun[qk]; // exact ref order
                    unsigned p = atomicAdd(&s.cnt, 1u);
                    if (p < CAP)
                        s.cand[p] = make_uint2(__float_as_uint(pv),
                                               (unsigned)(qk * NC + ck));
                }
            }
        }
    }
}

// Compact list of rows whose chunk bound can reach thbits.
__device__ void build_rows(Smem& s, unsigned thbits, int tid) {
    __syncthreads();
    if (tid == 0) s.nrows = 0;
    __syncthreads();
    for (int q = tid; q < NQ; q += NT)
        if (__float_as_uint(s.Pm2[q]) >= thbits)
            s.rowlist[atomicAdd(&s.nrows, 1u)] = q;
    __syncthreads();
}

// Dense walk over owned chunks of listed rows. Row q owns chunks
// [ceil(81q/4), ceil(81(q+1)/4)) — disjoint & complete; any element with
// key >= th lies in a chunk whose owner row passes the Pm2 test.
template <bool COLLECT>
__device__ void scan_rows(Smem& s, const float4* __restrict__ lg4,
                          unsigned thbits, int tid) {
    const int total = (int)s.nrows * 21;
    for (int idx = tid; idx < total; idx += NT) {
        int r  = idx / 21;                  // magic-mul, compile-time const
        int j  = idx - r * 21;
        int q  = s.rowlist[r];
        int e0 = NC * q;
        int i4 = ((e0 + 3) >> 2) + j;
        if (4 * i4 < e0 + NC) {             // inside this row's owned range
            float4 v4 = lg4[i4];
            proc_chunk<COLLECT>(s, v4, q, 4 * i4 - e0, thbits);
        }
    }
}

__device__ void collect80(Smem& s, unsigned thbits, int tid) {
    for (int q = tid; q < NQ; q += NT) {
        unsigned u = __float_as_uint(s.last[q]);   // key == precise for class 80
        if (u >= thbits) {
            unsigned p = atomicAdd(&s.cnt, 1u);
            if (p < CAP) s.cand[p] = make_uint2(u, (unsigned)(q * NC + 80));
        }
    }
}

__global__ __launch_bounds__(NT) void postprocess_kernel(
    const float* __restrict__ logits,   // [B, Q, C]
    const float* __restrict__ obj,      // [B, Q]
    const float* __restrict__ boxes,    // [B, Q, 4] cx cy w h
    const float* __restrict__ unk,      // [B, Q]
    const float* __restrict__ tsz,      // [B, 2]  (h, w)
    float* __restrict__ out)            // scores[B*K] | labels[B*K] | boxes[B*K*4]
{
    __shared__ Smem s;
    const int b   = blockIdx.x;
    const int tid = threadIdx.x;
    const float4* lg4 = (const float4*)(logits + (size_t)b * QC);

    // ---- init ----
    *(uint4*)&s.hist[tid * 4] = make_uint4(0u, 0u, 0u, 0u);
    if (tid == 0) s.cnt = 0;
    for (int q = tid; q < NQ; q += NT) {
        float op = expf(-obj[b * NQ + q]);
        float un = sigmoidf(unk[b * NQ + q]);
        float om = 1.f - un;
        s.op[q] = op; s.omun[q] = om; s.P[q] = op * om; s.last[q] = op * un;
    }
    __syncthreads();

    // row bounds + class-80 histogram (no logit reads needed)
    for (int q = tid; q < NQ; q += NT) {
        float pm = s.P[q];
        if (q + 1 < NQ) pm = fmaxf(pm, s.P[q + 1]);
        s.Pm2[q] = pm;
        atomicAdd(&s.hist[__float_as_uint(s.last[q]) >> 19], 1u);
    }

    // provisional threshold from class-80 alone (lower bound on final tF).
    unsigned t0 = scan_threshold(s, tid);

    // ---- pass 1: histogram over surviving rows only ----
    build_rows(s, t0 << 19, tid);
    scan_rows<false>(s, lg4, t0 << 19, tid);

    // final threshold: largest bin with >= TOPK keys at or above it
    unsigned tF = scan_threshold(s, tid);

    // ---- pass 2: collect at tF-1 bin floor (provable top-100 superset:
    // bin width ~6% rel >> 1e-4 total approx/reassoc error; L2-hot subset)
    unsigned thC = ((tF >= 1) ? tF - 1 : 0) << 19;
    build_rows(s, thC, tid);
    scan_rows<true>(s, lg4, thC, tid);
    collect80(s, thC, tid);
    __syncthreads();

    if (s.cnt > CAP) {
        // massive-tie pathology only; tighten to bin tF and re-collect
        // (thC rowlist is a superset of the tF rowlist — reuse it).
        __syncthreads();
        if (tid == 0) s.cnt = 0;
        __syncthreads();
        scan_rows<true>(s, lg4, tF << 19, tid);
        collect80(s, tF << 19, tid);
        __syncthreads();
    }

    const int m = (int)min(s.cnt, (unsigned)CAP);

    // ---- rank (exact; scores >= 0 so uint bit order == value order;
    //      tie-break lower flat index first, like lax.top_k) ----
    const float* bx = boxes + (size_t)b * NQ * 4;
    const float img_h = tsz[b * 2 + 0];
    const float img_w = tsz[b * 2 + 1];
    float* o_sc = out + (size_t)b * TOPK;
    float* o_lb = out + (size_t)BATCH * TOPK + (size_t)b * TOPK;
    float* o_bx = out + (size_t)2 * BATCH * TOPK + (size_t)b * TOPK * 4;

    for (int i = tid; i < m; i += NT) {
        uint2 ci = s.cand[i];
        int r = 0;
        for (int j = 0; j < m; ++j) {
            uint2 cj = s.cand[j];
            r += (cj.x > ci.x) || (cj.x == ci.x && cj.y < ci.y);
        }
        if (r < TOPK) {
            int ei = (int)ci.y;
            o_sc[r] = __uint_as_float(ci.x);
            o_lb[r] = (float)(ei % NC);
            int q = ei / NC;
            float cx = bx[q * 4 + 0];
            float cy = bx[q * 4 + 1];
            float w  = bx[q * 4 + 2];
            float h  = bx[q * 4 + 3];
            o_bx[r * 4 + 0] = (cx - 0.5f * w) * img_w;
            o_bx[r * 4 + 1] = (cy - 0.5f * h) * img_h;
            o_bx[r * 4 + 2] = (cx + 0.5f * w) * img_w;
            o_bx[r * 4 + 3] = (cy + 0.5f * h) * img_h;
        }
    }
}

extern "C" void kernel_launch(void* const* d_in, const int* in_sizes, int n_in,
                              void* d_out, int out_size, void* d_ws, size_t ws_size,
                              hipStream_t stream) {
    const float* pred_logits = (const float*)d_in[0];
    const float* pred_obj    = (const float*)d_in[1];
    const float* pred_boxes  = (const float*)d_in[2];
    const float* pred_unk    = (const float*)d_in[3];
    const float* target_sz   = (const float*)d_in[4];
    float* out = (float*)d_out;
    postprocess_kernel<<<BATCH, NT, 0, stream>>>(
        pred_logits, pred_obj, pred_boxes, pred_unk, target_sz, out);
}